// Round 5
// baseline (236.538 us; speedup 1.0000x reference)
//
#include <hip/hip_runtime.h>
#include <math.h>

#define NCOLS 4096
#define MROWS 4096
#define NLAYERS 5
#define RPB 16                // rows per fused block
#define NSPLIT (MROWS / RPB)  // 256 column-partial splits (== grid of main passes)
#define TPB 1024              // 16 waves/CU: latency hiding without extra traffic
#define SPER (NSPLIT / 8)     // 32 splits per thread-group in stage-2

__device__ __forceinline__ float sigf(float x) { return 1.0f / (1.0f + expf(-x)); }

// bf16 (packed in 32-bit words) -> float, exact
__device__ __forceinline__ float lo16(unsigned w) { return __uint_as_float(w << 16); }
__device__ __forceinline__ float hi16(unsigned w) { return __uint_as_float(w & 0xFFFF0000u); }

// float -> bf16 bits, round-to-nearest-even (A has no NaN/Inf)
__device__ __forceinline__ unsigned f2bf(float f) {
    unsigned u = __float_as_uint(f);
    return (u + 0x7FFFu + ((u >> 16) & 1u)) >> 16;
}

// uint2 (4 packed bf16) -> 4 floats
__device__ __forceinline__ void unpack4(uint2 u, float* a) {
    a[0] = lo16(u.x); a[1] = hi16(u.x); a[2] = lo16(u.y); a[3] = hi16(u.y);
}

// butterfly reductions, result broadcast to all 64 lanes
__device__ __forceinline__ float waveSum(float v) {
#pragma unroll
    for (int o = 32; o; o >>= 1) v += __shfl_xor(v, o, 64);
    return v;
}
__device__ __forceinline__ float waveMax(float v) {
#pragma unroll
    for (int o = 32; o; o >>= 1) v = fmaxf(v, __shfl_xor(v, o, 64));
    return v;
}

// 16-lane-segment reduce: lanes {0,16,32,48} end with their segment's result.
__device__ __forceinline__ float segSum16(float v) {
    v += __shfl_down(v, 8, 16);
    v += __shfl_down(v, 4, 16);
    v += __shfl_down(v, 2, 16);
    v += __shfl_down(v, 1, 16);
    return v;
}
__device__ __forceinline__ float segMax16(float v) {
    v = fmaxf(v, __shfl_down(v, 8, 16));
    v = fmaxf(v, __shfl_down(v, 4, 16));
    v = fmaxf(v, __shfl_down(v, 2, 16));
    v = fmaxf(v, __shfl_down(v, 1, 16));
    return v;
}

// ============ fused preamble: fp32 read, bf16 convert+store, rowsum->right_mask,
// ============ colsum partial p1, colmax(rm) partial p2 — ONE pass over fp32 A
__global__ __launch_bounds__(TPB) void k_pre_fused(
    const float* __restrict__ A, unsigned* __restrict__ Abf,
    const float* __restrict__ thqr, float* __restrict__ right_mask,
    float* __restrict__ one_r, float* __restrict__ y, float* __restrict__ p1,
    float* __restrict__ p2) {
    __shared__ float wp[RPB][64];  // 4 KB wave-partial staging
    __shared__ float s_rm[RPB];
    int t = threadIdx.x, s = blockIdx.x, r0 = s * RPB;
    int wv = t >> 6, lane = t & 63;
    const float4* a4 = reinterpret_cast<const float4*>(A);
    uint2* o2 = reinterpret_cast<uint2*>(Abf);
    uint2 w[RPB];
#pragma unroll
    for (int i = 0; i < RPB; i++) {
        float4 f = a4[(size_t)(r0 + i) * 1024 + t];
        uint2 u;
        u.x = f2bf(f.x) | (f2bf(f.y) << 16);
        u.y = f2bf(f.z) | (f2bf(f.w) << 16);
        w[i] = u;
        o2[(size_t)(r0 + i) * 1024 + t] = u;
        float v = (f.x + f.y) + (f.z + f.w);
        v = segSum16(v);
        if ((lane & 15) == 0) wp[i][(wv << 2) | (lane >> 4)] = v;
    }
    __syncthreads();
    {  // wave wv owns row wv
        float sv = waveSum(wp[wv][lane]);
        if (lane == 0) {
            float q = 0.f;
#pragma unroll
            for (int k = 0; k < 4; k++) q += sigf(thqr[2 * k] * sv + thqr[2 * k + 1]);
            float rmv = q * 0.25f;
            right_mask[r0 + wv] = rmv;
            one_r[r0 + wv] = 1.0f - rmv;
            y[r0 + wv] = 0.f;
            s_rm[wv] = rmv;
        }
    }
    __syncthreads();
    float cs[4], cm[4];
#pragma unroll
    for (int c = 0; c < 4; c++) { cs[c] = 0.f; cm[c] = -INFINITY; }
#pragma unroll
    for (int i = 0; i < RPB; i++) {
        float a[4];
        unpack4(w[i], a);
        float vi = s_rm[i];
#pragma unroll
        for (int c = 0; c < 4; c++) {
            cs[c] += a[c];
            cm[c] = fmaxf(cm[c], a[c] * vi);
        }
    }
    float4* q1 = reinterpret_cast<float4*>(p1 + (size_t)s * NCOLS + 4 * t);
    float4* q2 = reinterpret_cast<float4*>(p2 + (size_t)s * NCOLS + 4 * t);
    q1[0] = make_float4(cs[0], cs[1], cs[2], cs[3]);
    q2[0] = make_float4(cm[0], cm[1], cm[2], cm[3]);
}

// ============ fused: ro[i]=(A@b)*one_r  +  colmax partial p1 — ONE bf16 pass
__global__ __launch_bounds__(TPB) void k_ro_colmax(const unsigned* __restrict__ Abf,
                                                   const float* __restrict__ bvec,
                                                   const float* __restrict__ one_r,
                                                   float* __restrict__ ro,
                                                   float* __restrict__ p1) {
    __shared__ float wp[RPB][64];
    __shared__ float rol[RPB];
    int t = threadIdx.x, s = blockIdx.x, r0 = s * RPB;
    int wv = t >> 6, lane = t & 63;
    const uint2* a2 = reinterpret_cast<const uint2*>(Abf);
    const float4* b4 = reinterpret_cast<const float4*>(bvec);
    float4 bv = b4[t];
    float bb[4] = {bv.x, bv.y, bv.z, bv.w};
    uint2 w[RPB];
#pragma unroll
    for (int i = 0; i < RPB; i++) {
        w[i] = a2[(size_t)(r0 + i) * 1024 + t];
        float a[4];
        unpack4(w[i], a);
        float d = (a[0] * bb[0] + a[1] * bb[1]) + (a[2] * bb[2] + a[3] * bb[3]);
        d = segSum16(d);
        if ((lane & 15) == 0) wp[i][(wv << 2) | (lane >> 4)] = d;
    }
    __syncthreads();
    {
        float sv = waveSum(wp[wv][lane]);
        if (lane == 0) {
            float rv = sv * one_r[r0 + wv];
            ro[r0 + wv] = rv;
            rol[wv] = rv;
        }
    }
    __syncthreads();
    float cm[4];
#pragma unroll
    for (int c = 0; c < 4; c++) cm[c] = -INFINITY;
#pragma unroll
    for (int i = 0; i < RPB; i++) {
        float a[4];
        unpack4(w[i], a);
        float vi = rol[i];
#pragma unroll
        for (int c = 0; c < 4; c++) cm[c] = fmaxf(cm[c], a[c] * vi);
    }
    float4* q1 = reinterpret_cast<float4*>(p1 + (size_t)s * NCOLS + 4 * t);
    q1[0] = make_float4(cm[0], cm[1], cm[2], cm[3]);
}

// ============ fused: row max-product + g_theta + y update + dual partials
// FINAL=1 additionally computes pred_dual[row] = y_final + right_mask + A@hw.
template <int FINAL>
__global__ __launch_bounds__(TPB) void k_row_dual(
    const unsigned* __restrict__ Abf, const float* __restrict__ ro_t,
    const float* __restrict__ one_r, const float* __restrict__ ro,
    const float* __restrict__ tg, float* __restrict__ y, float* __restrict__ p1,
    float* __restrict__ p2, const float* __restrict__ hwv,
    const float* __restrict__ rm, float* __restrict__ out) {
    __shared__ float wpA[RPB][64];
    __shared__ float wpB[RPB][64];
    __shared__ float ydl[RPB];
    __shared__ float ydrol[RPB];
    int t = threadIdx.x, s = blockIdx.x, r0 = s * RPB;
    int wv = t >> 6, lane = t & 63;
    const uint2* a2 = reinterpret_cast<const uint2*>(Abf);
    const float4* v4 = reinterpret_cast<const float4*>(ro_t);
    float4 vq = v4[t];
    float vv[4] = {vq.x, vq.y, vq.z, vq.w};
    float hv[4];
    if (FINAL) {
        const float4* h4 = reinterpret_cast<const float4*>(hwv);
        float4 hq = h4[t];
        hv[0] = hq.x; hv[1] = hq.y; hv[2] = hq.z; hv[3] = hq.w;
    }
    uint2 w[RPB];
#pragma unroll
    for (int i = 0; i < RPB; i++) {
        w[i] = a2[(size_t)(r0 + i) * 1024 + t];
        float a[4];
        unpack4(w[i], a);
        float m = fmaxf(fmaxf(a[0] * vv[0], a[1] * vv[1]),
                        fmaxf(a[2] * vv[2], a[3] * vv[3]));
        m = segMax16(m);
        if ((lane & 15) == 0) wpA[i][(wv << 2) | (lane >> 4)] = m;
        if (FINAL) {
            float d = (a[0] * hv[0] + a[1] * hv[1]) + (a[2] * hv[2] + a[3] * hv[3]);
            d = segSum16(d);
            if ((lane & 15) == 0) wpB[i][(wv << 2) | (lane >> 4)] = d;
        }
    }
    __syncthreads();
    {  // wave wv owns row wv
        float m = waveMax(wpA[wv][lane]);
        float dd = 0.f;
        if (FINAL) dd = waveSum(wpB[wv][lane]);
        float oR = one_r[r0 + wv];
        float roi = ro[r0 + wv];
        float z = roi - m * oR * 0.5f;  // ro - ro_max/ALPHA
        float term = 0.f;
        if (lane < 16)
            term = tg[3 * lane] * sigf(tg[3 * lane + 1] * z + tg[3 * lane + 2]);
        float g = waveSum(term);
        float yd = g * oR;
        if (lane == 0) {
            float yn = (y[r0 + wv] + yd) * oR;
            y[r0 + wv] = yn;
            ydl[wv] = yd;
            ydrol[wv] = yd / roi;
            if (FINAL) out[NCOLS + r0 + wv] = yn + rm[r0 + wv] + dd;  // pred_dual
        }
    }
    __syncthreads();
    float s1[4], s2[4];
#pragma unroll
    for (int c = 0; c < 4; c++) { s1[c] = 0.f; s2[c] = 0.f; }
#pragma unroll
    for (int i = 0; i < RPB; i++) {
        float a[4];
        unpack4(w[i], a);
        float u = ydl[i];
        float q = ydrol[i];
#pragma unroll
        for (int c = 0; c < 4; c++) {
            s1[c] += a[c] * u;
            s2[c] += a[c] * q;
        }
    }
    float4* q1 = reinterpret_cast<float4*>(p1 + (size_t)s * NCOLS + 4 * t);
    float4* q2 = reinterpret_cast<float4*>(p2 + (size_t)s * NCOLS + 4 * t);
    q1[0] = make_float4(s1[0], s1[1], s1[2], s1[3]);
    q2[0] = make_float4(s2[0], s2[1], s2[2], s2[3]);
}

// ---------------- stage-2 reductions (parallel over splits) ----------------
// 128 blocks x 256 threads; 32 columns/block; 8 groups x SPER splits.

__global__ __launch_bounds__(256) void k_left(const float* __restrict__ p1,
                                              const float* __restrict__ p2,
                                              const float* __restrict__ thql,
                                              const float* __restrict__ h,
                                              const float* __restrict__ fptr,
                                              float* __restrict__ one_l,
                                              float* __restrict__ hw,
                                              float* __restrict__ r,
                                              float* __restrict__ b,
                                              float* __restrict__ x) {
    __shared__ float smS[256];
    __shared__ float smM[256];
    int jl = threadIdx.x & 31;
    int g = threadIdx.x >> 5;  // 0..7
    int j = blockIdx.x * 32 + jl;
    float cs = 0.f, cm = -INFINITY;
#pragma unroll
    for (int t = 0; t < SPER; t++) {
        int s = g * SPER + t;
        cs += p1[(size_t)s * NCOLS + j];
        cm = fmaxf(cm, p2[(size_t)s * NCOLS + j]);
    }
    smS[threadIdx.x] = cs;
    smM[threadIdx.x] = cm;
    __syncthreads();
    if (g == 0) {
#pragma unroll
        for (int gg = 1; gg < 8; gg++) {
            cs += smS[gg * 32 + jl];
            cm = fmaxf(cm, smM[gg * 32 + jl]);
        }
        float q = 0.f;
#pragma unroll
        for (int k = 0; k < 4; k++) q += sigf(thql[2 * k] * cs + thql[2 * k + 1]);
        float c1 = q * 0.25f;
        float lm = fmaxf(c1, cm);
        one_l[j] = 1.0f - lm;
        hw[j] = h[j] * lm / cs;
        r[j] = fptr[0];
        b[j] = 1.0f;
        x[j] = 0.f;
    }
}

__global__ __launch_bounds__(256) void k_rot(const float* __restrict__ p,
                                             const float* __restrict__ one_l,
                                             float* __restrict__ ro_t) {
    __shared__ float smM[256];
    int jl = threadIdx.x & 31;
    int g = threadIdx.x >> 5;
    int j = blockIdx.x * 32 + jl;
    float m = -INFINITY;
#pragma unroll
    for (int t = 0; t < SPER; t++) {
        int s = g * SPER + t;
        m = fmaxf(m, p[(size_t)s * NCOLS + j]);
    }
    smM[threadIdx.x] = m;
    __syncthreads();
    if (g == 0) {
#pragma unroll
        for (int gg = 1; gg < 8; gg++) m = fmaxf(m, smM[gg * 32 + jl]);
        ro_t[j] = m * one_l[j];
    }
}

__global__ __launch_bounds__(256) void k_epilogue(const float* __restrict__ p1,
                                                  const float* __restrict__ p2,
                                                  const float* __restrict__ one_l,
                                                  const float* __restrict__ tb,
                                                  const float* __restrict__ fptr,
                                                  float* __restrict__ r,
                                                  float* __restrict__ b,
                                                  float* __restrict__ x,
                                                  float* __restrict__ out, int last) {
    __shared__ float smA[256];
    __shared__ float smB[256];
    int jl = threadIdx.x & 31;
    int g = threadIdx.x >> 5;
    int j = blockIdx.x * 32 + jl;
    float s1 = 0.f, s2 = 0.f;
#pragma unroll
    for (int t = 0; t < SPER; t++) {
        int s = g * SPER + t;
        s1 += p1[(size_t)s * NCOLS + j];
        s2 += p2[(size_t)s * NCOLS + j];
    }
    smA[threadIdx.x] = s1;
    smB[threadIdx.x] = s2;
    __syncthreads();
    if (g == 0) {
#pragma unroll
        for (int gg = 1; gg < 8; gg++) {
            s1 += smA[gg * 32 + jl];
            s2 += smB[gg * 32 + jl];
        }
        float oL = one_l[j];
        float rj = (r[j] - fmaxf(s1, 0.f)) * oL;
        float xj = (x[j] + b[j] * s2) * oL;
        float fv = fptr[0];
        float bb = 0.f;
#pragma unroll
        for (int k = 0; k < 16; k++) {
            float ak = tb[4 * k], bk = tb[4 * k + 1], ck = tb[4 * k + 2],
                  dk = tb[4 * k + 3];
            bb += ak * sigf(bk * rj + ck) * exp2f(-fmaxf(dk * (rj - fv), 0.f));
        }
        r[j] = rj;
        x[j] = xj;
        if (last) out[j] = xj;  // pred_primal
        b[j] = bb * oL;
    }
}

extern "C" void kernel_launch(void* const* d_in, const int* in_sizes, int n_in,
                              void* d_out, int out_size, void* d_ws, size_t ws_size,
                              hipStream_t stream) {
    const float* A = (const float*)d_in[0];
    const float* theta_g = (const float*)d_in[1];  // (5,16,3)
    const float* theta_b = (const float*)d_in[2];  // (5,16,4)
    const float* fptr = (const float*)d_in[3];     // scalar
    const float* h = (const float*)d_in[4];        // (N,)
    const float* thql = (const float*)d_in[5];     // (4,2)
    const float* thqr = (const float*)d_in[6];     // (4,2)
    float* out = (float*)d_out;  // [0:4096]=pred_primal(x), [4096:8192]=pred_dual

    // workspace layout (floats)
    float* ws = (float*)d_ws;
    float* right_mask = ws + 0 * 4096;
    float* one_r = ws + 1 * 4096;
    float* one_l = ws + 2 * 4096;
    float* hwv = ws + 3 * 4096;
    float* ro = ws + 4 * 4096;
    float* ro_t = ws + 5 * 4096;
    float* r = ws + 6 * 4096;
    float* b = ws + 7 * 4096;
    float* x = ws + 8 * 4096;
    float* y = ws + 9 * 4096;
    float* p1 = ws + 12 * 4096;
    float* p2 = p1 + (size_t)NSPLIT * NCOLS;
    unsigned* Abf = (unsigned*)(p2 + (size_t)NSPLIT * NCOLS);  // 32 MB bf16 copy

    // preamble: ONE pass over fp32 A (convert + rowsum/right_mask + col partials)
    k_pre_fused<<<NSPLIT, TPB, 0, stream>>>(A, Abf, thqr, right_mask, one_r, y, p1, p2);
    k_left<<<128, 256, 0, stream>>>(p1, p2, thql, h, fptr, one_l, hwv, r, b, x);

    // layers: last k_row_dual also emits pred_dual; last epilogue emits pred_primal
    for (int l = 0; l < NLAYERS; l++) {
        k_ro_colmax<<<NSPLIT, TPB, 0, stream>>>(Abf, b, one_r, ro, p1);
        k_rot<<<128, 256, 0, stream>>>(p1, one_l, ro_t);
        if (l < NLAYERS - 1)
            k_row_dual<0><<<NSPLIT, TPB, 0, stream>>>(Abf, ro_t, one_r, ro,
                                                      theta_g + l * 48, y, p1, p2, hwv,
                                                      right_mask, out);
        else
            k_row_dual<1><<<NSPLIT, TPB, 0, stream>>>(Abf, ro_t, one_r, ro,
                                                      theta_g + l * 48, y, p1, p2, hwv,
                                                      right_mask, out);
        k_epilogue<<<128, 256, 0, stream>>>(p1, p2, one_l, theta_b + l * 64, fptr, r, b,
                                            x, out, l == NLAYERS - 1);
    }
}

// Round 6
// 209.379 us; speedup vs baseline: 1.1297x; 1.1297x over previous
//
#include <hip/hip_runtime.h>
#include <math.h>

#define NCOLS 4096
#define MROWS 4096
#define NLAYERS 5
#define RPB 16                // rows per fused block
#define NSPLIT (MROWS / RPB)  // 256 column-partial splits
#define SPER (NSPLIT / 8)     // 32 splits per thread-group in stage-2

__device__ __forceinline__ float sigf(float x) { return 1.0f / (1.0f + expf(-x)); }

// bf16 (packed in 32-bit words) -> float, exact
__device__ __forceinline__ float lo16(unsigned w) { return __uint_as_float(w << 16); }
__device__ __forceinline__ float hi16(unsigned w) { return __uint_as_float(w & 0xFFFF0000u); }

// float -> bf16 bits, round-to-nearest-even (A has no NaN/Inf)
__device__ __forceinline__ unsigned f2bf(float f) {
    unsigned u = __float_as_uint(f);
    return (u + 0x7FFFu + ((u >> 16) & 1u)) >> 16;
}

__device__ __forceinline__ void unpack8(uint4 w, float* a) {
    a[0] = lo16(w.x); a[1] = hi16(w.x); a[2] = lo16(w.y); a[3] = hi16(w.y);
    a[4] = lo16(w.z); a[5] = hi16(w.z); a[6] = lo16(w.w); a[7] = hi16(w.w);
}

// 512-thread block: reduce prt[16][512] along the 512 axis -> res[16]
__device__ __forceinline__ void waveReduceRows(const float (*prt)[512], float* res,
                                               bool isMax) {
    int wid = threadIdx.x >> 6;  // 0..7
    int lane = threadIdx.x & 63;
#pragma unroll
    for (int rr = 0; rr < 2; rr++) {
        int row = wid * 2 + rr;
        if (isMax) {
            float v = -INFINITY;
#pragma unroll
            for (int k = 0; k < 8; k++) v = fmaxf(v, prt[row][lane + 64 * k]);
#pragma unroll
            for (int o = 32; o; o >>= 1) v = fmaxf(v, __shfl_down(v, o, 64));
            if (lane == 0) res[row] = v;
        } else {
            float v = 0.f;
#pragma unroll
            for (int k = 0; k < 8; k++) v += prt[row][lane + 64 * k];
#pragma unroll
            for (int o = 32; o; o >>= 1) v += __shfl_down(v, o, 64);
            if (lane == 0) res[row] = v;
        }
    }
}

// ============ fused preamble: fp32 read, bf16 convert+store, rowsum->right_mask,
// ============ colsum partial p1, colmax(rm) partial p2 — ONE pass over fp32 A
__global__ __launch_bounds__(512) void k_pre_fused(
    const float* __restrict__ A, unsigned* __restrict__ Abf,
    const float* __restrict__ thqr, float* __restrict__ right_mask,
    float* __restrict__ one_r, float* __restrict__ y, float* __restrict__ p1,
    float* __restrict__ p2) {
    __shared__ float prt[RPB][512];
    __shared__ float res[RPB];
    __shared__ float rml[RPB];
    int t = threadIdx.x, s = blockIdx.x, r0 = s * RPB;
    const float4* a4 = reinterpret_cast<const float4*>(A);
    uint4* o4 = reinterpret_cast<uint4*>(Abf);
    uint4 w[RPB];
#pragma unroll
    for (int i = 0; i < RPB; i++) {
        size_t base = (size_t)(r0 + i) * 1024 + 2 * t;
        float4 fA = a4[base];
        float4 fB = a4[base + 1];
        prt[i][t] = ((fA.x + fA.y) + (fA.z + fA.w)) + ((fB.x + fB.y) + (fB.z + fB.w));
        uint4 u;
        u.x = f2bf(fA.x) | (f2bf(fA.y) << 16);
        u.y = f2bf(fA.z) | (f2bf(fA.w) << 16);
        u.z = f2bf(fB.x) | (f2bf(fB.y) << 16);
        u.w = f2bf(fB.z) | (f2bf(fB.w) << 16);
        w[i] = u;
        o4[(size_t)(r0 + i) * 512 + t] = u;
    }
    __syncthreads();
    waveReduceRows(prt, res, false);
    __syncthreads();
    if (t < RPB) {
        float sv = res[t];
        float q = 0.f;
#pragma unroll
        for (int k = 0; k < 4; k++) q += sigf(thqr[2 * k] * sv + thqr[2 * k + 1]);
        float rmv = q * 0.25f;
        right_mask[r0 + t] = rmv;
        one_r[r0 + t] = 1.0f - rmv;
        y[r0 + t] = 0.f;
        rml[t] = rmv;
    }
    __syncthreads();
    float cs[8], cm[8];
#pragma unroll
    for (int c = 0; c < 8; c++) { cs[c] = 0.f; cm[c] = -INFINITY; }
#pragma unroll
    for (int i = 0; i < RPB; i++) {
        float a[8];
        unpack8(w[i], a);
        float vi = rml[i];
#pragma unroll
        for (int c = 0; c < 8; c++) {
            cs[c] += a[c];
            cm[c] = fmaxf(cm[c], a[c] * vi);
        }
    }
    float4* q1 = reinterpret_cast<float4*>(p1 + (size_t)s * NCOLS + 8 * t);
    float4* q2 = reinterpret_cast<float4*>(p2 + (size_t)s * NCOLS + 8 * t);
    q1[0] = make_float4(cs[0], cs[1], cs[2], cs[3]);
    q1[1] = make_float4(cs[4], cs[5], cs[6], cs[7]);
    q2[0] = make_float4(cm[0], cm[1], cm[2], cm[3]);
    q2[1] = make_float4(cm[4], cm[5], cm[6], cm[7]);
}

// ============ fused: ro[i]=(A@b)*one_r  +  colmax partial p1 — ONE bf16 pass
__global__ __launch_bounds__(512) void k_ro_colmax(const unsigned* __restrict__ Abf,
                                                   const float* __restrict__ bvec,
                                                   const float* __restrict__ one_r,
                                                   float* __restrict__ ro,
                                                   float* __restrict__ p1) {
    __shared__ float prt[RPB][512];
    __shared__ float res[RPB];
    __shared__ float rol[RPB];
    int t = threadIdx.x, s = blockIdx.x, r0 = s * RPB;
    const uint4* a8 = reinterpret_cast<const uint4*>(Abf);
    const float4* b4 = reinterpret_cast<const float4*>(bvec);
    float4 bA = b4[2 * t];
    float4 bB = b4[2 * t + 1];
    float bb[8] = {bA.x, bA.y, bA.z, bA.w, bB.x, bB.y, bB.z, bB.w};
    uint4 w[RPB];
#pragma unroll
    for (int i = 0; i < RPB; i++) {
        w[i] = a8[(size_t)(r0 + i) * 512 + t];
        float a[8];
        unpack8(w[i], a);
        float d = 0.f;
#pragma unroll
        for (int c = 0; c < 8; c++) d += a[c] * bb[c];
        prt[i][t] = d;
    }
    __syncthreads();
    waveReduceRows(prt, res, false);
    __syncthreads();
    if (t < RPB) {
        float rv = res[t] * one_r[r0 + t];
        ro[r0 + t] = rv;
        rol[t] = rv;
    }
    __syncthreads();
    float cm[8];
#pragma unroll
    for (int c = 0; c < 8; c++) cm[c] = -INFINITY;
#pragma unroll
    for (int i = 0; i < RPB; i++) {
        float a[8];
        unpack8(w[i], a);
        float vi = rol[i];
#pragma unroll
        for (int c = 0; c < 8; c++) cm[c] = fmaxf(cm[c], a[c] * vi);
    }
    float4* q1 = reinterpret_cast<float4*>(p1 + (size_t)s * NCOLS + 8 * t);
    q1[0] = make_float4(cm[0], cm[1], cm[2], cm[3]);
    q1[1] = make_float4(cm[4], cm[5], cm[6], cm[7]);
}

// ============ fused: row max-product + g_theta + y update + dual partials — ONE pass
// FINAL=1 additionally computes pred_dual[row] = y_final + right_mask + A@hw,
// reusing the registers already holding the row (kills the k_final_dual pass).
template <int FINAL>
__global__ __launch_bounds__(512) void k_row_dual(
    const unsigned* __restrict__ Abf, const float* __restrict__ ro_t,
    const float* __restrict__ one_r, const float* __restrict__ ro,
    const float* __restrict__ tg, float* __restrict__ y, float* __restrict__ p1,
    float* __restrict__ p2, const float* __restrict__ hwv,
    const float* __restrict__ rm, float* __restrict__ out) {
    __shared__ float prt[RPB][512];
    __shared__ float prt2[FINAL ? RPB : 1][512];
    __shared__ float res[RPB];
    __shared__ float res2[FINAL ? RPB : 1];
    __shared__ float ydl[RPB];
    __shared__ float ydrol[RPB];
    int t = threadIdx.x, s = blockIdx.x, r0 = s * RPB;
    const uint4* a8 = reinterpret_cast<const uint4*>(Abf);
    const float4* v4 = reinterpret_cast<const float4*>(ro_t);
    float4 vA = v4[2 * t];
    float4 vB = v4[2 * t + 1];
    float vv[8] = {vA.x, vA.y, vA.z, vA.w, vB.x, vB.y, vB.z, vB.w};
    float hv[8];
    if (FINAL) {
        const float4* h4 = reinterpret_cast<const float4*>(hwv);
        float4 hA = h4[2 * t];
        float4 hB = h4[2 * t + 1];
        hv[0] = hA.x; hv[1] = hA.y; hv[2] = hA.z; hv[3] = hA.w;
        hv[4] = hB.x; hv[5] = hB.y; hv[6] = hB.z; hv[7] = hB.w;
    }
    uint4 w[RPB];
#pragma unroll
    for (int i = 0; i < RPB; i++) {
        w[i] = a8[(size_t)(r0 + i) * 512 + t];
        float a[8];
        unpack8(w[i], a);
        float m = -INFINITY;
#pragma unroll
        for (int c = 0; c < 8; c++) m = fmaxf(m, a[c] * vv[c]);
        prt[i][t] = m;
        if (FINAL) {
            float d = 0.f;
#pragma unroll
            for (int c = 0; c < 8; c++) d += a[c] * hv[c];
            prt2[i][t] = d;
        }
    }
    __syncthreads();
    waveReduceRows(prt, res, true);
    if (FINAL) waveReduceRows(prt2, res2, false);
    __syncthreads();
    if (t < RPB) {
        float m = res[t];
        float oR = one_r[r0 + t];
        float roi = ro[r0 + t];
        float z = roi - m * oR * 0.5f;  // ro - ro_max/ALPHA
        float g = 0.f;
#pragma unroll
        for (int k = 0; k < 16; k++) {
            g += tg[3 * k] * sigf(tg[3 * k + 1] * z + tg[3 * k + 2]);
        }
        float yd = g * oR;
        float yn = (y[r0 + t] + yd) * oR;
        y[r0 + t] = yn;
        ydl[t] = yd;
        ydrol[t] = yd / roi;
        if (FINAL) out[NCOLS + r0 + t] = yn + rm[r0 + t] + res2[t];  // pred_dual
    }
    __syncthreads();
    float s1[8], s2[8];
#pragma unroll
    for (int c = 0; c < 8; c++) { s1[c] = 0.f; s2[c] = 0.f; }
#pragma unroll
    for (int i = 0; i < RPB; i++) {
        float a[8];
        unpack8(w[i], a);
        float u = ydl[i];
        float q = ydrol[i];
#pragma unroll
        for (int c = 0; c < 8; c++) {
            s1[c] += a[c] * u;
            s2[c] += a[c] * q;
        }
    }
    float4* q1 = reinterpret_cast<float4*>(p1 + (size_t)s * NCOLS + 8 * t);
    float4* q2 = reinterpret_cast<float4*>(p2 + (size_t)s * NCOLS + 8 * t);
    q1[0] = make_float4(s1[0], s1[1], s1[2], s1[3]);
    q1[1] = make_float4(s1[4], s1[5], s1[6], s1[7]);
    q2[0] = make_float4(s2[0], s2[1], s2[2], s2[3]);
    q2[1] = make_float4(s2[4], s2[5], s2[6], s2[7]);
}

// ---------------- stage-2 reductions (parallel over splits) ----------------
// 128 blocks x 256 threads; 32 columns/block; 8 groups x SPER splits.

__global__ __launch_bounds__(256) void k_left(const float* __restrict__ p1,
                                              const float* __restrict__ p2,
                                              const float* __restrict__ thql,
                                              const float* __restrict__ h,
                                              const float* __restrict__ fptr,
                                              float* __restrict__ one_l,
                                              float* __restrict__ hw,
                                              float* __restrict__ r,
                                              float* __restrict__ b,
                                              float* __restrict__ x) {
    __shared__ float smS[256];
    __shared__ float smM[256];
    int jl = threadIdx.x & 31;
    int g = threadIdx.x >> 5;  // 0..7
    int j = blockIdx.x * 32 + jl;
    float cs = 0.f, cm = -INFINITY;
#pragma unroll
    for (int t = 0; t < SPER; t++) {
        int s = g * SPER + t;
        cs += p1[(size_t)s * NCOLS + j];
        cm = fmaxf(cm, p2[(size_t)s * NCOLS + j]);
    }
    smS[threadIdx.x] = cs;
    smM[threadIdx.x] = cm;
    __syncthreads();
    if (g == 0) {
#pragma unroll
        for (int gg = 1; gg < 8; gg++) {
            cs += smS[gg * 32 + jl];
            cm = fmaxf(cm, smM[gg * 32 + jl]);
        }
        float q = 0.f;
#pragma unroll
        for (int k = 0; k < 4; k++) q += sigf(thql[2 * k] * cs + thql[2 * k + 1]);
        float c1 = q * 0.25f;
        float lm = fmaxf(c1, cm);
        one_l[j] = 1.0f - lm;
        hw[j] = h[j] * lm / cs;
        r[j] = fptr[0];
        b[j] = 1.0f;
        x[j] = 0.f;
    }
}

__global__ __launch_bounds__(256) void k_rot(const float* __restrict__ p,
                                             const float* __restrict__ one_l,
                                             float* __restrict__ ro_t) {
    __shared__ float smM[256];
    int jl = threadIdx.x & 31;
    int g = threadIdx.x >> 5;
    int j = blockIdx.x * 32 + jl;
    float m = -INFINITY;
#pragma unroll
    for (int t = 0; t < SPER; t++) {
        int s = g * SPER + t;
        m = fmaxf(m, p[(size_t)s * NCOLS + j]);
    }
    smM[threadIdx.x] = m;
    __syncthreads();
    if (g == 0) {
#pragma unroll
        for (int gg = 1; gg < 8; gg++) m = fmaxf(m, smM[gg * 32 + jl]);
        ro_t[j] = m * one_l[j];
    }
}

__global__ __launch_bounds__(256) void k_epilogue(const float* __restrict__ p1,
                                                  const float* __restrict__ p2,
                                                  const float* __restrict__ one_l,
                                                  const float* __restrict__ tb,
                                                  const float* __restrict__ fptr,
                                                  float* __restrict__ r,
                                                  float* __restrict__ b,
                                                  float* __restrict__ x,
                                                  float* __restrict__ out, int last) {
    __shared__ float smA[256];
    __shared__ float smB[256];
    int jl = threadIdx.x & 31;
    int g = threadIdx.x >> 5;
    int j = blockIdx.x * 32 + jl;
    float s1 = 0.f, s2 = 0.f;
#pragma unroll
    for (int t = 0; t < SPER; t++) {
        int s = g * SPER + t;
        s1 += p1[(size_t)s * NCOLS + j];
        s2 += p2[(size_t)s * NCOLS + j];
    }
    smA[threadIdx.x] = s1;
    smB[threadIdx.x] = s2;
    __syncthreads();
    if (g == 0) {
#pragma unroll
        for (int gg = 1; gg < 8; gg++) {
            s1 += smA[gg * 32 + jl];
            s2 += smB[gg * 32 + jl];
        }
        float oL = one_l[j];
        float rj = (r[j] - fmaxf(s1, 0.f)) * oL;
        float xj = (x[j] + b[j] * s2) * oL;
        float fv = fptr[0];
        float bb = 0.f;
#pragma unroll
        for (int k = 0; k < 16; k++) {
            float ak = tb[4 * k], bk = tb[4 * k + 1], ck = tb[4 * k + 2],
                  dk = tb[4 * k + 3];
            bb += ak * sigf(bk * rj + ck) * exp2f(-fmaxf(dk * (rj - fv), 0.f));
        }
        r[j] = rj;
        x[j] = xj;
        if (last) out[j] = xj;  // pred_primal
        b[j] = bb * oL;
    }
}

extern "C" void kernel_launch(void* const* d_in, const int* in_sizes, int n_in,
                              void* d_out, int out_size, void* d_ws, size_t ws_size,
                              hipStream_t stream) {
    const float* A = (const float*)d_in[0];
    const float* theta_g = (const float*)d_in[1];  // (5,16,3)
    const float* theta_b = (const float*)d_in[2];  // (5,16,4)
    const float* fptr = (const float*)d_in[3];     // scalar
    const float* h = (const float*)d_in[4];        // (N,)
    const float* thql = (const float*)d_in[5];     // (4,2)
    const float* thqr = (const float*)d_in[6];     // (4,2)
    float* out = (float*)d_out;  // [0:4096]=pred_primal(x), [4096:8192]=pred_dual

    // workspace layout (floats)
    float* ws = (float*)d_ws;
    float* right_mask = ws + 0 * 4096;
    float* one_r = ws + 1 * 4096;
    float* one_l = ws + 2 * 4096;
    float* hwv = ws + 3 * 4096;
    float* ro = ws + 4 * 4096;
    float* ro_t = ws + 5 * 4096;
    float* r = ws + 6 * 4096;
    float* b = ws + 7 * 4096;
    float* x = ws + 8 * 4096;
    float* y = ws + 9 * 4096;
    float* p1 = ws + 12 * 4096;
    float* p2 = p1 + (size_t)NSPLIT * NCOLS;
    unsigned* Abf = (unsigned*)(p2 + (size_t)NSPLIT * NCOLS);  // 32 MB bf16 copy

    // preamble: ONE pass over fp32 A (convert + rowsum/right_mask + col partials)
    k_pre_fused<<<NSPLIT, 512, 0, stream>>>(A, Abf, thqr, right_mask, one_r, y, p1, p2);
    k_left<<<128, 256, 0, stream>>>(p1, p2, thql, h, fptr, one_l, hwv, r, b, x);

    // layers: last k_row_dual also emits pred_dual; last epilogue emits pred_primal
    for (int l = 0; l < NLAYERS; l++) {
        k_ro_colmax<<<NSPLIT, 512, 0, stream>>>(Abf, b, one_r, ro, p1);
        k_rot<<<128, 256, 0, stream>>>(p1, one_l, ro_t);
        if (l < NLAYERS - 1)
            k_row_dual<0><<<NSPLIT, 512, 0, stream>>>(Abf, ro_t, one_r, ro,
                                                      theta_g + l * 48, y, p1, p2, hwv,
                                                      right_mask, out);
        else
            k_row_dual<1><<<NSPLIT, 512, 0, stream>>>(Abf, ro_t, one_r, ro,
                                                      theta_g + l * 48, y, p1, p2, hwv,
                                                      right_mask, out);
        k_epilogue<<<128, 256, 0, stream>>>(p1, p2, one_l, theta_b + l * 64, fptr, r, b,
                                            x, out, l == NLAYERS - 1);
    }
}

// Round 7
// 204.168 us; speedup vs baseline: 1.1585x; 1.0255x over previous
//
#include <hip/hip_runtime.h>
#include <math.h>

#define NCOLS 4096
#define MROWS 4096
#define NLAYERS 5
#define RPB 16                // rows per fused block
#define NSPLIT (MROWS / RPB)  // 256 column-partial splits
#define SPER (NSPLIT / 8)     // 32 splits per thread-group in stage-2

__device__ __forceinline__ float sigf(float x) { return 1.0f / (1.0f + expf(-x)); }

// bf16 (packed in 32-bit words) -> float, exact
__device__ __forceinline__ float lo16(unsigned w) { return __uint_as_float(w << 16); }
__device__ __forceinline__ float hi16(unsigned w) { return __uint_as_float(w & 0xFFFF0000u); }

// float -> bf16 bits, round-to-nearest-even (A has no NaN/Inf)
__device__ __forceinline__ unsigned f2bf(float f) {
    unsigned u = __float_as_uint(f);
    return (u + 0x7FFFu + ((u >> 16) & 1u)) >> 16;
}

__device__ __forceinline__ void unpack8(uint4 w, float* a) {
    a[0] = lo16(w.x); a[1] = hi16(w.x); a[2] = lo16(w.y); a[3] = hi16(w.y);
    a[4] = lo16(w.z); a[5] = hi16(w.z); a[6] = lo16(w.w); a[7] = hi16(w.w);
}

// ============ fused preamble: fp32 read, bf16 convert+store, rowsum->right_mask,
// ============ colsum partial p1, colmax(rm) partial p2 — ONE pass over fp32 A
__global__ __launch_bounds__(512) void k_pre_fused(
    const float* __restrict__ A, unsigned* __restrict__ Abf,
    const float* __restrict__ thqr, float* __restrict__ right_mask,
    float* __restrict__ one_r, float* __restrict__ y, float* __restrict__ p1,
    float* __restrict__ p2) {
    __shared__ float prt[RPB][512];
    __shared__ float rml[RPB];
    int t = threadIdx.x, s = blockIdx.x, r0 = s * RPB;
    int wid = t >> 6, lane = t & 63;
    const float4* a4 = reinterpret_cast<const float4*>(A);
    uint4* o4 = reinterpret_cast<uint4*>(Abf);
    uint4 w[RPB];
#pragma unroll
    for (int i = 0; i < RPB; i++) {
        size_t base = (size_t)(r0 + i) * 1024 + 2 * t;
        float4 fA = a4[base];
        float4 fB = a4[base + 1];
        prt[i][t] = ((fA.x + fA.y) + (fA.z + fA.w)) + ((fB.x + fB.y) + (fB.z + fB.w));
        uint4 u;
        u.x = f2bf(fA.x) | (f2bf(fA.y) << 16);
        u.y = f2bf(fA.z) | (f2bf(fA.w) << 16);
        u.z = f2bf(fB.x) | (f2bf(fB.y) << 16);
        u.w = f2bf(fB.z) | (f2bf(fB.w) << 16);
        w[i] = u;
        o4[(size_t)(r0 + i) * 512 + t] = u;
    }
    __syncthreads();
    // wave wid reduces rows 2wid,2wid+1; lane0 applies scalar tail inline
#pragma unroll
    for (int rr = 0; rr < 2; rr++) {
        int row = wid * 2 + rr;
        float v = 0.f;
#pragma unroll
        for (int k = 0; k < 8; k++) v += prt[row][lane + 64 * k];
#pragma unroll
        for (int o = 32; o; o >>= 1) v += __shfl_down(v, o, 64);
        if (lane == 0) {
            float q = 0.f;
#pragma unroll
            for (int k = 0; k < 4; k++) q += sigf(thqr[2 * k] * v + thqr[2 * k + 1]);
            float rmv = q * 0.25f;
            right_mask[r0 + row] = rmv;
            one_r[r0 + row] = 1.0f - rmv;
            y[r0 + row] = 0.f;
            rml[row] = rmv;
        }
    }
    __syncthreads();
    float cs[8], cm[8];
#pragma unroll
    for (int c = 0; c < 8; c++) { cs[c] = 0.f; cm[c] = -INFINITY; }
#pragma unroll
    for (int i = 0; i < RPB; i++) {
        float a[8];
        unpack8(w[i], a);
        float vi = rml[i];
#pragma unroll
        for (int c = 0; c < 8; c++) {
            cs[c] += a[c];
            cm[c] = fmaxf(cm[c], a[c] * vi);
        }
    }
    float4* q1 = reinterpret_cast<float4*>(p1 + (size_t)s * NCOLS + 8 * t);
    float4* q2 = reinterpret_cast<float4*>(p2 + (size_t)s * NCOLS + 8 * t);
    q1[0] = make_float4(cs[0], cs[1], cs[2], cs[3]);
    q1[1] = make_float4(cs[4], cs[5], cs[6], cs[7]);
    q2[0] = make_float4(cm[0], cm[1], cm[2], cm[3]);
    q2[1] = make_float4(cm[4], cm[5], cm[6], cm[7]);
}

// ============ fused: ro[i]=(A@b)*one_r  +  colmax partial p1 — ONE bf16 pass
__global__ __launch_bounds__(512) void k_ro_colmax(const unsigned* __restrict__ Abf,
                                                   const float* __restrict__ bvec,
                                                   const float* __restrict__ one_r,
                                                   float* __restrict__ ro,
                                                   float* __restrict__ p1) {
    __shared__ float prt[RPB][512];
    __shared__ float rol[RPB];
    int t = threadIdx.x, s = blockIdx.x, r0 = s * RPB;
    int wid = t >> 6, lane = t & 63;
    const uint4* a8 = reinterpret_cast<const uint4*>(Abf);
    const float4* b4 = reinterpret_cast<const float4*>(bvec);
    float4 bA = b4[2 * t];
    float4 bB = b4[2 * t + 1];
    float bb[8] = {bA.x, bA.y, bA.z, bA.w, bB.x, bB.y, bB.z, bB.w};
    uint4 w[RPB];
#pragma unroll
    for (int i = 0; i < RPB; i++) {
        w[i] = a8[(size_t)(r0 + i) * 512 + t];
        float a[8];
        unpack8(w[i], a);
        float d = 0.f;
#pragma unroll
        for (int c = 0; c < 8; c++) d += a[c] * bb[c];
        prt[i][t] = d;
    }
    __syncthreads();
    // wave wid reduces rows 2wid,2wid+1; lane0 applies one_r inline
#pragma unroll
    for (int rr = 0; rr < 2; rr++) {
        int row = wid * 2 + rr;
        float v = 0.f;
#pragma unroll
        for (int k = 0; k < 8; k++) v += prt[row][lane + 64 * k];
#pragma unroll
        for (int o = 32; o; o >>= 1) v += __shfl_down(v, o, 64);
        if (lane == 0) {
            float rv = v * one_r[r0 + row];
            ro[r0 + row] = rv;
            rol[row] = rv;
        }
    }
    __syncthreads();
    float cm[8];
#pragma unroll
    for (int c = 0; c < 8; c++) cm[c] = -INFINITY;
#pragma unroll
    for (int i = 0; i < RPB; i++) {
        float a[8];
        unpack8(w[i], a);
        float vi = rol[i];
#pragma unroll
        for (int c = 0; c < 8; c++) cm[c] = fmaxf(cm[c], a[c] * vi);
    }
    float4* q1 = reinterpret_cast<float4*>(p1 + (size_t)s * NCOLS + 8 * t);
    q1[0] = make_float4(cm[0], cm[1], cm[2], cm[3]);
    q1[1] = make_float4(cm[4], cm[5], cm[6], cm[7]);
}

// ============ fused: row max-product + g_theta + y update + dual partials — ONE pass
// FINAL=1 additionally computes pred_dual[row] = y_final + right_mask + A@hw.
// g_theta parallelized: lanes 0-15 handle row 2wid, lanes 16-31 row 2wid+1.
template <int FINAL>
__global__ __launch_bounds__(512) void k_row_dual(
    const unsigned* __restrict__ Abf, const float* __restrict__ ro_t,
    const float* __restrict__ one_r, const float* __restrict__ ro,
    const float* __restrict__ tg, float* __restrict__ y, float* __restrict__ p1,
    float* __restrict__ p2, const float* __restrict__ hwv,
    const float* __restrict__ rm, float* __restrict__ out) {
    __shared__ float prt[RPB][512];
    __shared__ float prt2[FINAL ? RPB : 1][512];
    __shared__ float ydl[RPB];
    __shared__ float ydrol[RPB];
    int t = threadIdx.x, s = blockIdx.x, r0 = s * RPB;
    int wid = t >> 6, lane = t & 63;
    const uint4* a8 = reinterpret_cast<const uint4*>(Abf);
    const float4* v4 = reinterpret_cast<const float4*>(ro_t);
    float4 vA = v4[2 * t];
    float4 vB = v4[2 * t + 1];
    float vv[8] = {vA.x, vA.y, vA.z, vA.w, vB.x, vB.y, vB.z, vB.w};
    float hv[8];
    if (FINAL) {
        const float4* h4 = reinterpret_cast<const float4*>(hwv);
        float4 hA = h4[2 * t];
        float4 hB = h4[2 * t + 1];
        hv[0] = hA.x; hv[1] = hA.y; hv[2] = hA.z; hv[3] = hA.w;
        hv[4] = hB.x; hv[5] = hB.y; hv[6] = hB.z; hv[7] = hB.w;
    }
    uint4 w[RPB];
#pragma unroll
    for (int i = 0; i < RPB; i++) {
        w[i] = a8[(size_t)(r0 + i) * 512 + t];
        float a[8];
        unpack8(w[i], a);
        float m = -INFINITY;
#pragma unroll
        for (int c = 0; c < 8; c++) m = fmaxf(m, a[c] * vv[c]);
        prt[i][t] = m;
        if (FINAL) {
            float d = 0.f;
#pragma unroll
            for (int c = 0; c < 8; c++) d += a[c] * hv[c];
            prt2[i][t] = d;
        }
    }
    __syncthreads();
    // wave wid: butterfly-reduce rows 2wid, 2wid+1 (result in ALL lanes),
    // then lanes 0-31 compute the 16 g_theta terms for the two rows in parallel.
    float m0, m1, d0 = 0.f, d1 = 0.f;
    {
        float v = -INFINITY;
#pragma unroll
        for (int k = 0; k < 8; k++) v = fmaxf(v, prt[wid * 2][lane + 64 * k]);
#pragma unroll
        for (int o = 32; o; o >>= 1) v = fmaxf(v, __shfl_xor(v, o, 64));
        m0 = v;
        v = -INFINITY;
#pragma unroll
        for (int k = 0; k < 8; k++) v = fmaxf(v, prt[wid * 2 + 1][lane + 64 * k]);
#pragma unroll
        for (int o = 32; o; o >>= 1) v = fmaxf(v, __shfl_xor(v, o, 64));
        m1 = v;
        if (FINAL) {
            float d = 0.f;
#pragma unroll
            for (int k = 0; k < 8; k++) d += prt2[wid * 2][lane + 64 * k];
#pragma unroll
            for (int o = 32; o; o >>= 1) d += __shfl_xor(d, o, 64);
            d0 = d;
            d = 0.f;
#pragma unroll
            for (int k = 0; k < 8; k++) d += prt2[wid * 2 + 1][lane + 64 * k];
#pragma unroll
            for (int o = 32; o; o >>= 1) d += __shfl_xor(d, o, 64);
            d1 = d;
        }
    }
    if (lane < 32) {
        int rr = lane >> 4;  // 0: row 2wid (lanes 0-15), 1: row 2wid+1 (lanes 16-31)
        int row = wid * 2 + rr;
        float m = rr ? m1 : m0;
        float oR = one_r[r0 + row];
        float roi = ro[r0 + row];
        float z = roi - m * oR * 0.5f;  // ro - ro_max/ALPHA
        int kk = lane & 15;
        float term = tg[3 * kk] * sigf(tg[3 * kk + 1] * z + tg[3 * kk + 2]);
        term += __shfl_down(term, 8, 16);
        term += __shfl_down(term, 4, 16);
        term += __shfl_down(term, 2, 16);
        term += __shfl_down(term, 1, 16);
        if (kk == 0) {
            float yd = term * oR;
            float yn = (y[r0 + row] + yd) * oR;
            y[r0 + row] = yn;
            ydl[row] = yd;
            ydrol[row] = yd / roi;
            if (FINAL) {
                float dd = rr ? d1 : d0;
                out[NCOLS + r0 + row] = yn + rm[r0 + row] + dd;  // pred_dual
            }
        }
    }
    __syncthreads();
    float s1[8], s2[8];
#pragma unroll
    for (int c = 0; c < 8; c++) { s1[c] = 0.f; s2[c] = 0.f; }
#pragma unroll
    for (int i = 0; i < RPB; i++) {
        float a[8];
        unpack8(w[i], a);
        float u = ydl[i];
        float q = ydrol[i];
#pragma unroll
        for (int c = 0; c < 8; c++) {
            s1[c] += a[c] * u;
            s2[c] += a[c] * q;
        }
    }
    float4* q1 = reinterpret_cast<float4*>(p1 + (size_t)s * NCOLS + 8 * t);
    float4* q2 = reinterpret_cast<float4*>(p2 + (size_t)s * NCOLS + 8 * t);
    q1[0] = make_float4(s1[0], s1[1], s1[2], s1[3]);
    q1[1] = make_float4(s1[4], s1[5], s1[6], s1[7]);
    q2[0] = make_float4(s2[0], s2[1], s2[2], s2[3]);
    q2[1] = make_float4(s2[4], s2[5], s2[6], s2[7]);
}

// ---------------- stage-2 reductions (parallel over splits) ----------------
// 128 blocks x 256 threads; 32 columns/block; 8 groups x SPER splits.

__global__ __launch_bounds__(256) void k_left(const float* __restrict__ p1,
                                              const float* __restrict__ p2,
                                              const float* __restrict__ thql,
                                              const float* __restrict__ h,
                                              const float* __restrict__ fptr,
                                              float* __restrict__ one_l,
                                              float* __restrict__ hw,
                                              float* __restrict__ r,
                                              float* __restrict__ b,
                                              float* __restrict__ x) {
    __shared__ float smS[256];
    __shared__ float smM[256];
    int jl = threadIdx.x & 31;
    int g = threadIdx.x >> 5;  // 0..7
    int j = blockIdx.x * 32 + jl;
    float cs = 0.f, cm = -INFINITY;
#pragma unroll
    for (int t = 0; t < SPER; t++) {
        int s = g * SPER + t;
        cs += p1[(size_t)s * NCOLS + j];
        cm = fmaxf(cm, p2[(size_t)s * NCOLS + j]);
    }
    smS[threadIdx.x] = cs;
    smM[threadIdx.x] = cm;
    __syncthreads();
    if (g == 0) {
#pragma unroll
        for (int gg = 1; gg < 8; gg++) {
            cs += smS[gg * 32 + jl];
            cm = fmaxf(cm, smM[gg * 32 + jl]);
        }
        float q = 0.f;
#pragma unroll
        for (int k = 0; k < 4; k++) q += sigf(thql[2 * k] * cs + thql[2 * k + 1]);
        float c1 = q * 0.25f;
        float lm = fmaxf(c1, cm);
        one_l[j] = 1.0f - lm;
        hw[j] = h[j] * lm / cs;
        r[j] = fptr[0];
        b[j] = 1.0f;
        x[j] = 0.f;
    }
}

__global__ __launch_bounds__(256) void k_rot(const float* __restrict__ p,
                                             const float* __restrict__ one_l,
                                             float* __restrict__ ro_t) {
    __shared__ float smM[256];
    int jl = threadIdx.x & 31;
    int g = threadIdx.x >> 5;
    int j = blockIdx.x * 32 + jl;
    float m = -INFINITY;
#pragma unroll
    for (int t = 0; t < SPER; t++) {
        int s = g * SPER + t;
        m = fmaxf(m, p[(size_t)s * NCOLS + j]);
    }
    smM[threadIdx.x] = m;
    __syncthreads();
    if (g == 0) {
#pragma unroll
        for (int gg = 1; gg < 8; gg++) m = fmaxf(m, smM[gg * 32 + jl]);
        ro_t[j] = m * one_l[j];
    }
}

__global__ __launch_bounds__(256) void k_epilogue(const float* __restrict__ p1,
                                                  const float* __restrict__ p2,
                                                  const float* __restrict__ one_l,
                                                  const float* __restrict__ tb,
                                                  const float* __restrict__ fptr,
                                                  float* __restrict__ r,
                                                  float* __restrict__ b,
                                                  float* __restrict__ x,
                                                  float* __restrict__ out, int last) {
    __shared__ float smA[256];
    __shared__ float smB[256];
    int jl = threadIdx.x & 31;
    int g = threadIdx.x >> 5;
    int j = blockIdx.x * 32 + jl;
    float s1 = 0.f, s2 = 0.f;
#pragma unroll
    for (int t = 0; t < SPER; t++) {
        int s = g * SPER + t;
        s1 += p1[(size_t)s * NCOLS + j];
        s2 += p2[(size_t)s * NCOLS + j];
    }
    smA[threadIdx.x] = s1;
    smB[threadIdx.x] = s2;
    __syncthreads();
    if (g == 0) {
#pragma unroll
        for (int gg = 1; gg < 8; gg++) {
            s1 += smA[gg * 32 + jl];
            s2 += smB[gg * 32 + jl];
        }
        float oL = one_l[j];
        float rj = (r[j] - fmaxf(s1, 0.f)) * oL;
        float xj = (x[j] + b[j] * s2) * oL;
        float fv = fptr[0];
        float bb = 0.f;
#pragma unroll
        for (int k = 0; k < 16; k++) {
            float ak = tb[4 * k], bk = tb[4 * k + 1], ck = tb[4 * k + 2],
                  dk = tb[4 * k + 3];
            bb += ak * sigf(bk * rj + ck) * exp2f(-fmaxf(dk * (rj - fv), 0.f));
        }
        r[j] = rj;
        x[j] = xj;
        if (last) out[j] = xj;  // pred_primal
        b[j] = bb * oL;
    }
}

extern "C" void kernel_launch(void* const* d_in, const int* in_sizes, int n_in,
                              void* d_out, int out_size, void* d_ws, size_t ws_size,
                              hipStream_t stream) {
    const float* A = (const float*)d_in[0];
    const float* theta_g = (const float*)d_in[1];  // (5,16,3)
    const float* theta_b = (const float*)d_in[2];  // (5,16,4)
    const float* fptr = (const float*)d_in[3];     // scalar
    const float* h = (const float*)d_in[4];        // (N,)
    const float* thql = (const float*)d_in[5];     // (4,2)
    const float* thqr = (const float*)d_in[6];     // (4,2)
    float* out = (float*)d_out;  // [0:4096]=pred_primal(x), [4096:8192]=pred_dual

    // workspace layout (floats)
    float* ws = (float*)d_ws;
    float* right_mask = ws + 0 * 4096;
    float* one_r = ws + 1 * 4096;
    float* one_l = ws + 2 * 4096;
    float* hwv = ws + 3 * 4096;
    float* ro = ws + 4 * 4096;
    float* ro_t = ws + 5 * 4096;
    float* r = ws + 6 * 4096;
    float* b = ws + 7 * 4096;
    float* x = ws + 8 * 4096;
    float* y = ws + 9 * 4096;
    float* p1 = ws + 12 * 4096;
    float* p2 = p1 + (size_t)NSPLIT * NCOLS;
    unsigned* Abf = (unsigned*)(p2 + (size_t)NSPLIT * NCOLS);  // 32 MB bf16 copy

    // preamble: ONE pass over fp32 A (convert + rowsum/right_mask + col partials)
    k_pre_fused<<<NSPLIT, 512, 0, stream>>>(A, Abf, thqr, right_mask, one_r, y, p1, p2);
    k_left<<<128, 256, 0, stream>>>(p1, p2, thql, h, fptr, one_l, hwv, r, b, x);

    // layers: last k_row_dual also emits pred_dual; last epilogue emits pred_primal
    for (int l = 0; l < NLAYERS; l++) {
        k_ro_colmax<<<NSPLIT, 512, 0, stream>>>(Abf, b, one_r, ro, p1);
        k_rot<<<128, 256, 0, stream>>>(p1, one_l, ro_t);
        if (l < NLAYERS - 1)
            k_row_dual<0><<<NSPLIT, 512, 0, stream>>>(Abf, ro_t, one_r, ro,
                                                      theta_g + l * 48, y, p1, p2, hwv,
                                                      right_mask, out);
        else
            k_row_dual<1><<<NSPLIT, 512, 0, stream>>>(Abf, ro_t, one_r, ro,
                                                      theta_g + l * 48, y, p1, p2, hwv,
                                                      right_mask, out);
        k_epilogue<<<128, 256, 0, stream>>>(p1, p2, one_l, theta_b + l * 64, fptr, r, b,
                                            x, out, l == NLAYERS - 1);
    }
}

// Round 8
// 164.122 us; speedup vs baseline: 1.4412x; 1.2440x over previous
//
#include <hip/hip_runtime.h>
#include <math.h>

#define NCOLS 4096
#define MROWS 4096
#define NLAYERS 5
#define RPB 16                // rows per fused block
#define NSPLIT (MROWS / RPB)  // 256 column-partial splits
// stage-2: 256 blocks x 256 threads; 16 cols/block; 16 groups x 16 splits
#define S2SP (NSPLIT / 16)

__device__ __forceinline__ float sigf(float x) { return 1.0f / (1.0f + expf(-x)); }

// bf16 (packed in 32-bit words) -> float, exact
__device__ __forceinline__ float lo16(unsigned w) { return __uint_as_float(w << 16); }
__device__ __forceinline__ float hi16(unsigned w) { return __uint_as_float(w & 0xFFFF0000u); }

// float -> bf16 bits, round-to-nearest-even (A has no NaN/Inf)
__device__ __forceinline__ unsigned f2bf(float f) {
    unsigned u = __float_as_uint(f);
    return (u + 0x7FFFu + ((u >> 16) & 1u)) >> 16;
}

__device__ __forceinline__ void unpack8(uint4 w, float* a) {
    a[0] = lo16(w.x); a[1] = hi16(w.x); a[2] = lo16(w.y); a[3] = hi16(w.y);
    a[4] = lo16(w.z); a[5] = hi16(w.z); a[6] = lo16(w.w); a[7] = hi16(w.w);
}

// ============ fused preamble: fp32 read, bf16 convert+store, rowsum->right_mask,
// ============ colsum partial p1, colmax(rm) partial p2 — ONE pass over fp32 A
__global__ __launch_bounds__(512) void k_pre_fused(
    const float* __restrict__ A, unsigned* __restrict__ Abf,
    const float* __restrict__ thqr, float* __restrict__ right_mask,
    float* __restrict__ one_r, float* __restrict__ y, float* __restrict__ p1,
    float* __restrict__ p2) {
    __shared__ float prt[RPB][512];
    __shared__ float rml[RPB];
    int t = threadIdx.x, s = blockIdx.x, r0 = s * RPB;
    int wid = t >> 6, lane = t & 63;
    const float4* a4 = reinterpret_cast<const float4*>(A);
    uint4* o4 = reinterpret_cast<uint4*>(Abf);
    uint4 w[RPB];
#pragma unroll
    for (int i = 0; i < RPB; i++) {
        size_t base = (size_t)(r0 + i) * 1024 + 2 * t;
        float4 fA = a4[base];
        float4 fB = a4[base + 1];
        prt[i][t] = ((fA.x + fA.y) + (fA.z + fA.w)) + ((fB.x + fB.y) + (fB.z + fB.w));
        uint4 u;
        u.x = f2bf(fA.x) | (f2bf(fA.y) << 16);
        u.y = f2bf(fA.z) | (f2bf(fA.w) << 16);
        u.z = f2bf(fB.x) | (f2bf(fB.y) << 16);
        u.w = f2bf(fB.z) | (f2bf(fB.w) << 16);
        w[i] = u;
        o4[(size_t)(r0 + i) * 512 + t] = u;
    }
    __syncthreads();
    // wave wid reduces rows 2wid,2wid+1; lane0 applies scalar tail inline
#pragma unroll
    for (int rr = 0; rr < 2; rr++) {
        int row = wid * 2 + rr;
        float v = 0.f;
#pragma unroll
        for (int k = 0; k < 8; k++) v += prt[row][lane + 64 * k];
#pragma unroll
        for (int o = 32; o; o >>= 1) v += __shfl_down(v, o, 64);
        if (lane == 0) {
            float q = 0.f;
#pragma unroll
            for (int k = 0; k < 4; k++) q += sigf(thqr[2 * k] * v + thqr[2 * k + 1]);
            float rmv = q * 0.25f;
            right_mask[r0 + row] = rmv;
            one_r[r0 + row] = 1.0f - rmv;
            y[r0 + row] = 0.f;
            rml[row] = rmv;
        }
    }
    __syncthreads();
    float cs[8], cm[8];
#pragma unroll
    for (int c = 0; c < 8; c++) { cs[c] = 0.f; cm[c] = -INFINITY; }
#pragma unroll
    for (int i = 0; i < RPB; i++) {
        float a[8];
        unpack8(w[i], a);
        float vi = rml[i];
#pragma unroll
        for (int c = 0; c < 8; c++) {
            cs[c] += a[c];
            cm[c] = fmaxf(cm[c], a[c] * vi);
        }
    }
    float4* q1 = reinterpret_cast<float4*>(p1 + (size_t)s * NCOLS + 8 * t);
    float4* q2 = reinterpret_cast<float4*>(p2 + (size_t)s * NCOLS + 8 * t);
    q1[0] = make_float4(cs[0], cs[1], cs[2], cs[3]);
    q1[1] = make_float4(cs[4], cs[5], cs[6], cs[7]);
    q2[0] = make_float4(cm[0], cm[1], cm[2], cm[3]);
    q2[1] = make_float4(cm[4], cm[5], cm[6], cm[7]);
}

// ============ fused: ro[i]=(A@b)*one_r  +  colmax partial p1 — ONE bf16 pass
__global__ __launch_bounds__(512) void k_ro_colmax(const unsigned* __restrict__ Abf,
                                                   const float* __restrict__ bvec,
                                                   const float* __restrict__ one_r,
                                                   float* __restrict__ ro,
                                                   float* __restrict__ p1) {
    __shared__ float prt[RPB][512];
    __shared__ float rol[RPB];
    int t = threadIdx.x, s = blockIdx.x, r0 = s * RPB;
    int wid = t >> 6, lane = t & 63;
    const uint4* a8 = reinterpret_cast<const uint4*>(Abf);
    const float4* b4 = reinterpret_cast<const float4*>(bvec);
    float4 bA = b4[2 * t];
    float4 bB = b4[2 * t + 1];
    float bb[8] = {bA.x, bA.y, bA.z, bA.w, bB.x, bB.y, bB.z, bB.w};
    uint4 w[RPB];
#pragma unroll
    for (int i = 0; i < RPB; i++) {
        w[i] = a8[(size_t)(r0 + i) * 512 + t];
        float a[8];
        unpack8(w[i], a);
        float d = 0.f;
#pragma unroll
        for (int c = 0; c < 8; c++) d += a[c] * bb[c];
        prt[i][t] = d;
    }
    __syncthreads();
    // wave wid reduces rows 2wid,2wid+1; lane0 applies one_r inline
#pragma unroll
    for (int rr = 0; rr < 2; rr++) {
        int row = wid * 2 + rr;
        float v = 0.f;
#pragma unroll
        for (int k = 0; k < 8; k++) v += prt[row][lane + 64 * k];
#pragma unroll
        for (int o = 32; o; o >>= 1) v += __shfl_down(v, o, 64);
        if (lane == 0) {
            float rv = v * one_r[r0 + row];
            ro[r0 + row] = rv;
            rol[row] = rv;
        }
    }
    __syncthreads();
    float cm[8];
#pragma unroll
    for (int c = 0; c < 8; c++) cm[c] = -INFINITY;
#pragma unroll
    for (int i = 0; i < RPB; i++) {
        float a[8];
        unpack8(w[i], a);
        float vi = rol[i];
#pragma unroll
        for (int c = 0; c < 8; c++) cm[c] = fmaxf(cm[c], a[c] * vi);
    }
    float4* q1 = reinterpret_cast<float4*>(p1 + (size_t)s * NCOLS + 8 * t);
    q1[0] = make_float4(cm[0], cm[1], cm[2], cm[3]);
    q1[1] = make_float4(cm[4], cm[5], cm[6], cm[7]);
}

// ============ fused: row max-product + g_theta + y update + dual partials — ONE pass
// FINAL=1 additionally computes pred_dual[row] = y_final + right_mask + A@hw.
// g_theta parallelized: lanes 0-15 handle row 2wid, lanes 16-31 row 2wid+1.
template <int FINAL>
__global__ __launch_bounds__(512) void k_row_dual(
    const unsigned* __restrict__ Abf, const float* __restrict__ ro_t,
    const float* __restrict__ one_r, const float* __restrict__ ro,
    const float* __restrict__ tg, float* __restrict__ y, float* __restrict__ p1,
    float* __restrict__ p2, const float* __restrict__ hwv,
    const float* __restrict__ rm, float* __restrict__ out) {
    __shared__ float prt[RPB][512];
    __shared__ float prt2[FINAL ? RPB : 1][512];
    __shared__ float ydl[RPB];
    __shared__ float ydrol[RPB];
    int t = threadIdx.x, s = blockIdx.x, r0 = s * RPB;
    int wid = t >> 6, lane = t & 63;
    const uint4* a8 = reinterpret_cast<const uint4*>(Abf);
    const float4* v4 = reinterpret_cast<const float4*>(ro_t);
    float4 vA = v4[2 * t];
    float4 vB = v4[2 * t + 1];
    float vv[8] = {vA.x, vA.y, vA.z, vA.w, vB.x, vB.y, vB.z, vB.w};
    float hv[8];
    if (FINAL) {
        const float4* h4 = reinterpret_cast<const float4*>(hwv);
        float4 hA = h4[2 * t];
        float4 hB = h4[2 * t + 1];
        hv[0] = hA.x; hv[1] = hA.y; hv[2] = hA.z; hv[3] = hA.w;
        hv[4] = hB.x; hv[5] = hB.y; hv[6] = hB.z; hv[7] = hB.w;
    }
    uint4 w[RPB];
#pragma unroll
    for (int i = 0; i < RPB; i++) {
        w[i] = a8[(size_t)(r0 + i) * 512 + t];
        float a[8];
        unpack8(w[i], a);
        float m = -INFINITY;
#pragma unroll
        for (int c = 0; c < 8; c++) m = fmaxf(m, a[c] * vv[c]);
        prt[i][t] = m;
        if (FINAL) {
            float d = 0.f;
#pragma unroll
            for (int c = 0; c < 8; c++) d += a[c] * hv[c];
            prt2[i][t] = d;
        }
    }
    __syncthreads();
    // wave wid: butterfly-reduce rows 2wid, 2wid+1 (result in ALL lanes),
    // then lanes 0-31 compute the 16 g_theta terms for the two rows in parallel.
    float m0, m1, d0 = 0.f, d1 = 0.f;
    {
        float v = -INFINITY;
#pragma unroll
        for (int k = 0; k < 8; k++) v = fmaxf(v, prt[wid * 2][lane + 64 * k]);
#pragma unroll
        for (int o = 32; o; o >>= 1) v = fmaxf(v, __shfl_xor(v, o, 64));
        m0 = v;
        v = -INFINITY;
#pragma unroll
        for (int k = 0; k < 8; k++) v = fmaxf(v, prt[wid * 2 + 1][lane + 64 * k]);
#pragma unroll
        for (int o = 32; o; o >>= 1) v = fmaxf(v, __shfl_xor(v, o, 64));
        m1 = v;
        if (FINAL) {
            float d = 0.f;
#pragma unroll
            for (int k = 0; k < 8; k++) d += prt2[wid * 2][lane + 64 * k];
#pragma unroll
            for (int o = 32; o; o >>= 1) d += __shfl_xor(d, o, 64);
            d0 = d;
            d = 0.f;
#pragma unroll
            for (int k = 0; k < 8; k++) d += prt2[wid * 2 + 1][lane + 64 * k];
#pragma unroll
            for (int o = 32; o; o >>= 1) d += __shfl_xor(d, o, 64);
            d1 = d;
        }
    }
    if (lane < 32) {
        int rr = lane >> 4;  // 0: row 2wid (lanes 0-15), 1: row 2wid+1 (lanes 16-31)
        int row = wid * 2 + rr;
        float m = rr ? m1 : m0;
        float oR = one_r[r0 + row];
        float roi = ro[r0 + row];
        float z = roi - m * oR * 0.5f;  // ro - ro_max/ALPHA
        int kk = lane & 15;
        float term = tg[3 * kk] * sigf(tg[3 * kk + 1] * z + tg[3 * kk + 2]);
        term += __shfl_down(term, 8, 16);
        term += __shfl_down(term, 4, 16);
        term += __shfl_down(term, 2, 16);
        term += __shfl_down(term, 1, 16);
        if (kk == 0) {
            float yd = term * oR;
            float yn = (y[r0 + row] + yd) * oR;
            y[r0 + row] = yn;
            ydl[row] = yd;
            ydrol[row] = yd / roi;
            if (FINAL) {
                float dd = rr ? d1 : d0;
                out[NCOLS + r0 + row] = yn + rm[r0 + row] + dd;  // pred_dual
            }
        }
    }
    __syncthreads();
    float s1[8], s2[8];
#pragma unroll
    for (int c = 0; c < 8; c++) { s1[c] = 0.f; s2[c] = 0.f; }
#pragma unroll
    for (int i = 0; i < RPB; i++) {
        float a[8];
        unpack8(w[i], a);
        float u = ydl[i];
        float q = ydrol[i];
#pragma unroll
        for (int c = 0; c < 8; c++) {
            s1[c] += a[c] * u;
            s2[c] += a[c] * q;
        }
    }
    float4* q1 = reinterpret_cast<float4*>(p1 + (size_t)s * NCOLS + 8 * t);
    float4* q2 = reinterpret_cast<float4*>(p2 + (size_t)s * NCOLS + 8 * t);
    q1[0] = make_float4(s1[0], s1[1], s1[2], s1[3]);
    q1[1] = make_float4(s1[4], s1[5], s1[6], s1[7]);
    q2[0] = make_float4(s2[0], s2[1], s2[2], s2[3]);
    q2[1] = make_float4(s2[4], s2[5], s2[6], s2[7]);
}

// ---------------- stage-2 reductions (parallel over splits) ----------------
// 256 blocks x 256 threads (1 block/CU); 16 columns/block; 16 groups x 16 splits.

__global__ __launch_bounds__(256) void k_left(const float* __restrict__ p1,
                                              const float* __restrict__ p2,
                                              const float* __restrict__ thql,
                                              const float* __restrict__ h,
                                              const float* __restrict__ fptr,
                                              float* __restrict__ one_l,
                                              float* __restrict__ hw,
                                              float* __restrict__ r,
                                              float* __restrict__ b,
                                              float* __restrict__ x) {
    __shared__ float smS[256];
    __shared__ float smM[256];
    int jl = threadIdx.x & 15;
    int g = threadIdx.x >> 4;  // 0..15
    int j = blockIdx.x * 16 + jl;
    float cs = 0.f, cm = -INFINITY;
#pragma unroll
    for (int t = 0; t < S2SP; t++) {
        int s = g * S2SP + t;
        cs += p1[(size_t)s * NCOLS + j];
        cm = fmaxf(cm, p2[(size_t)s * NCOLS + j]);
    }
    smS[threadIdx.x] = cs;
    smM[threadIdx.x] = cm;
    __syncthreads();
    if (g == 0) {
#pragma unroll
        for (int gg = 1; gg < 16; gg++) {
            cs += smS[gg * 16 + jl];
            cm = fmaxf(cm, smM[gg * 16 + jl]);
        }
        float q = 0.f;
#pragma unroll
        for (int k = 0; k < 4; k++) q += sigf(thql[2 * k] * cs + thql[2 * k + 1]);
        float c1 = q * 0.25f;
        float lm = fmaxf(c1, cm);
        one_l[j] = 1.0f - lm;
        hw[j] = h[j] * lm / cs;
        r[j] = fptr[0];
        b[j] = 1.0f;
        x[j] = 0.f;
    }
}

__global__ __launch_bounds__(256) void k_rot(const float* __restrict__ p,
                                             const float* __restrict__ one_l,
                                             float* __restrict__ ro_t) {
    __shared__ float smM[256];
    int jl = threadIdx.x & 15;
    int g = threadIdx.x >> 4;
    int j = blockIdx.x * 16 + jl;
    float m = -INFINITY;
#pragma unroll
    for (int t = 0; t < S2SP; t++) {
        int s = g * S2SP + t;
        m = fmaxf(m, p[(size_t)s * NCOLS + j]);
    }
    smM[threadIdx.x] = m;
    __syncthreads();
    if (g == 0) {
#pragma unroll
        for (int gg = 1; gg < 16; gg++) m = fmaxf(m, smM[gg * 16 + jl]);
        ro_t[j] = m * one_l[j];
    }
}

__global__ __launch_bounds__(256) void k_epilogue(const float* __restrict__ p1,
                                                  const float* __restrict__ p2,
                                                  const float* __restrict__ one_l,
                                                  const float* __restrict__ tb,
                                                  const float* __restrict__ fptr,
                                                  float* __restrict__ r,
                                                  float* __restrict__ b,
                                                  float* __restrict__ x,
                                                  float* __restrict__ out, int last) {
    __shared__ float smA[256];
    __shared__ float smB[256];
    int jl = threadIdx.x & 15;
    int g = threadIdx.x >> 4;
    int j = blockIdx.x * 16 + jl;
    float s1 = 0.f, s2 = 0.f;
#pragma unroll
    for (int t = 0; t < S2SP; t++) {
        int s = g * S2SP + t;
        s1 += p1[(size_t)s * NCOLS + j];
        s2 += p2[(size_t)s * NCOLS + j];
    }
    smA[threadIdx.x] = s1;
    smB[threadIdx.x] = s2;
    __syncthreads();
    if (g == 0) {
#pragma unroll
        for (int gg = 1; gg < 16; gg++) {
            s1 += smA[gg * 16 + jl];
            s2 += smB[gg * 16 + jl];
        }
        float oL = one_l[j];
        float rj = (r[j] - fmaxf(s1, 0.f)) * oL;
        float xj = (x[j] + b[j] * s2) * oL;
        float fv = fptr[0];
        float bb = 0.f;
#pragma unroll
        for (int k = 0; k < 16; k++) {
            float ak = tb[4 * k], bk = tb[4 * k + 1], ck = tb[4 * k + 2],
                  dk = tb[4 * k + 3];
            bb += ak * sigf(bk * rj + ck) * exp2f(-fmaxf(dk * (rj - fv), 0.f));
        }
        r[j] = rj;
        x[j] = xj;
        if (last) out[j] = xj;  // pred_primal
        b[j] = bb * oL;
    }
}

extern "C" void kernel_launch(void* const* d_in, const int* in_sizes, int n_in,
                              void* d_out, int out_size, void* d_ws, size_t ws_size,
                              hipStream_t stream) {
    const float* A = (const float*)d_in[0];
    const float* theta_g = (const float*)d_in[1];  // (5,16,3)
    const float* theta_b = (const float*)d_in[2];  // (5,16,4)
    const float* fptr = (const float*)d_in[3];     // scalar
    const float* h = (const float*)d_in[4];        // (N,)
    const float* thql = (const float*)d_in[5];     // (4,2)
    const float* thqr = (const float*)d_in[6];     // (4,2)
    float* out = (float*)d_out;  // [0:4096]=pred_primal(x), [4096:8192]=pred_dual

    // workspace layout (floats)
    float* ws = (float*)d_ws;
    float* right_mask = ws + 0 * 4096;
    float* one_r = ws + 1 * 4096;
    float* one_l = ws + 2 * 4096;
    float* hwv = ws + 3 * 4096;
    float* ro = ws + 4 * 4096;
    float* ro_t = ws + 5 * 4096;
    float* r = ws + 6 * 4096;
    float* b = ws + 7 * 4096;
    float* x = ws + 8 * 4096;
    float* y = ws + 9 * 4096;
    float* p1 = ws + 12 * 4096;
    float* p2 = p1 + (size_t)NSPLIT * NCOLS;
    unsigned* Abf = (unsigned*)(p2 + (size_t)NSPLIT * NCOLS);  // 32 MB bf16 copy

    // preamble: ONE pass over fp32 A (convert + rowsum/right_mask + col partials)
    k_pre_fused<<<NSPLIT, 512, 0, stream>>>(A, Abf, thqr, right_mask, one_r, y, p1, p2);
    k_left<<<256, 256, 0, stream>>>(p1, p2, thql, h, fptr, one_l, hwv, r, b, x);

    // layers: last k_row_dual also emits pred_dual; last epilogue emits pred_primal
    for (int l = 0; l < NLAYERS; l++) {
        k_ro_colmax<<<NSPLIT, 512, 0, stream>>>(Abf, b, one_r, ro, p1);
        k_rot<<<256, 256, 0, stream>>>(p1, one_l, ro_t);
        if (l < NLAYERS - 1)
            k_row_dual<0><<<NSPLIT, 512, 0, stream>>>(Abf, ro_t, one_r, ro,
                                                      theta_g + l * 48, y, p1, p2, hwv,
                                                      right_mask, out);
        else
            k_row_dual<1><<<NSPLIT, 512, 0, stream>>>(Abf, ro_t, one_r, ro,
                                                      theta_g + l * 48, y, p1, p2, hwv,
                                                      right_mask, out);
        k_epilogue<<<256, 256, 0, stream>>>(p1, p2, one_l, theta_b + l * 64, fptr, r, b,
                                            x, out, l == NLAYERS - 1);
    }
}